// Round 9
// baseline (238.576 us; speedup 1.0000x reference)
//
#include <hip/hip_runtime.h>
#include <math.h>

#define NTOT 16384
#define NSEG 2048
#define CROWS 8385ull   // 129 rows * 65 floats per task (chunk tables + boundary row)

// ws float offsets
#define OFF_HH   0ull         // 16384*256 (hc reuses after layer-1 chunkv)
#define OFF_XC   4194304ull   // 16384*256
#define OFF_S1H  8388608ull   // 65536
#define OFF_S2H  8454144ull   // 65536
#define OFF_S1O  8519680ull   // 16384
#define OFF_S2O  8536064ull   // 16384
#define OFF_SVAL 8552448ull   // 32*2048
#define OFF_SIDX 8617984ull   // 32*2048 ints
#define OFF_CHA  8683520ull   // 32*8385
#define OFF_CHS  8951840ull   // 32*8385
#define OFF_VS   9220160ull   // 32*2048*64 -> end 13414464 floats (53.7 MB)

__device__ inline unsigned long long pack_key(float v, int idx) {
    unsigned u = __float_as_uint(v);
    u = (u & 0x80000000u) ? ~u : (u | 0x80000000u);
    return ((unsigned long long)u << 32) | (unsigned)idx;
}
__device__ inline float unpack_key(unsigned long long k) {
    unsigned u = (unsigned)(k >> 32);
    u = (u & 0x80000000u) ? (u ^ 0x80000000u) : ~u;
    return __uint_as_float(u);
}

// ---------------- GEMM 1 + fused s1/s2 projection (verified) ----------------
__global__ __launch_bounds__(256) void gemm1_k(const float* __restrict__ X,
                                               const float* __restrict__ Wh,
                                               const float* __restrict__ aH,
                                               float* __restrict__ hh,
                                               float* __restrict__ s1h,
                                               float* __restrict__ s2h) {
    __shared__ float As[64][68];
    __shared__ float Bs[64][68];
    const int tid = threadIdx.x;
    const int bm = blockIdx.x, h = blockIdx.y;
    const int c0 = tid & 63, r0 = tid >> 6;
#pragma unroll
    for (int r = 0; r < 16; ++r) {
        int row = r0 + r * 4;
        As[c0][row] = X[(size_t)(bm * 64 + row) * 64 + c0];
        Bs[row][c0] = Wh[h * 4096 + row * 64 + c0];
    }
    __syncthreads();
    const int tx = tid & 15, ty = tid >> 4;
    const int m0 = ty * 4, n0 = tx * 4;
    float acc[4][4] = {};
#pragma unroll
    for (int kk = 0; kk < 64; ++kk) {
        float4 a = *(const float4*)&As[kk][m0];
        float4 b = *(const float4*)&Bs[kk][n0];
        acc[0][0] += a.x * b.x; acc[0][1] += a.x * b.y; acc[0][2] += a.x * b.z; acc[0][3] += a.x * b.w;
        acc[1][0] += a.y * b.x; acc[1][1] += a.y * b.y; acc[1][2] += a.y * b.z; acc[1][3] += a.y * b.w;
        acc[2][0] += a.z * b.x; acc[2][1] += a.z * b.y; acc[2][2] += a.z * b.z; acc[2][3] += a.z * b.w;
        acc[3][0] += a.w * b.x; acc[3][1] += a.w * b.y; acc[3][2] += a.w * b.z; acc[3][3] += a.w * b.w;
    }
#pragma unroll
    for (int i = 0; i < 4; ++i) {
        float4 v = make_float4(acc[i][0], acc[i][1], acc[i][2], acc[i][3]);
        *(float4*)&hh[(size_t)(bm * 64 + m0 + i) * 256 + h * 64 + n0] = v;
    }
#pragma unroll
    for (int i = 0; i < 4; ++i) {
        float p1 = 0.f, p2 = 0.f;
#pragma unroll
        for (int jj = 0; jj < 4; ++jj) {
            p1 += acc[i][jj] * aH[h * 128 + n0 + jj];
            p2 += acc[i][jj] * aH[h * 128 + 64 + n0 + jj];
        }
#pragma unroll
        for (int off = 8; off; off >>= 1) {
            p1 += __shfl_xor(p1, off, 16);
            p2 += __shfl_xor(p2, off, 16);
        }
        if (tx == 0) {
            s1h[h * NTOT + bm * 64 + m0 + i] = p1;
            s2h[h * NTOT + bm * 64 + m0 + i] = p2;
        }
    }
}

// ---------------- GEMM 2 + fused s1/s2 projection (verified) ----------------
__global__ __launch_bounds__(256) void gemm2_k(const float* __restrict__ XC,
                                               const float* __restrict__ Wo,
                                               const float* __restrict__ aO,
                                               float* __restrict__ hc,
                                               float* __restrict__ s1o,
                                               float* __restrict__ s2o) {
    __shared__ float As[64][68];
    __shared__ float Bs[64][68];
    const int tid = threadIdx.x;
    const int bm = blockIdx.x;
    const int c0 = tid & 63, r0 = tid >> 6;
    const int tx = tid & 15, ty = tid >> 4;
    const int m0 = ty * 4, n0 = tx * 4;
    float acc[4][4] = {};
    for (int kt = 0; kt < 4; ++kt) {
#pragma unroll
        for (int r = 0; r < 16; ++r) {
            int row = r0 + r * 4;
            As[c0][row] = XC[(size_t)(bm * 64 + row) * 256 + kt * 64 + c0];
            Bs[row][c0] = Wo[(kt * 64 + row) * 64 + c0];
        }
        __syncthreads();
#pragma unroll
        for (int kk = 0; kk < 64; ++kk) {
            float4 a = *(const float4*)&As[kk][m0];
            float4 b = *(const float4*)&Bs[kk][n0];
            acc[0][0] += a.x * b.x; acc[0][1] += a.x * b.y; acc[0][2] += a.x * b.z; acc[0][3] += a.x * b.w;
            acc[1][0] += a.y * b.x; acc[1][1] += a.y * b.y; acc[1][2] += a.y * b.z; acc[1][3] += a.y * b.w;
            acc[2][0] += a.z * b.x; acc[2][1] += a.z * b.y; acc[2][2] += a.z * b.z; acc[2][3] += a.z * b.w;
            acc[3][0] += a.w * b.x; acc[3][1] += a.w * b.y; acc[3][2] += a.w * b.z; acc[3][3] += a.w * b.w;
        }
        __syncthreads();
    }
#pragma unroll
    for (int i = 0; i < 4; ++i) {
        float4 v = make_float4(acc[i][0], acc[i][1], acc[i][2], acc[i][3]);
        *(float4*)&hc[(size_t)(bm * 64 + m0 + i) * 64 + n0] = v;
    }
#pragma unroll
    for (int i = 0; i < 4; ++i) {
        float p1 = 0.f, p2 = 0.f;
#pragma unroll
        for (int jj = 0; jj < 4; ++jj) {
            p1 += acc[i][jj] * aO[n0 + jj];
            p2 += acc[i][jj] * aO[64 + n0 + jj];
        }
#pragma unroll
        for (int off = 8; off; off >>= 1) {
            p1 += __shfl_xor(p1, off, 16);
            p2 += __shfl_xor(p2, off, 16);
        }
        if (tx == 0) {
            s1o[bm * 64 + m0 + i] = p1;
            s2o[bm * 64 + m0 + i] = p2;
        }
    }
}

// ---- rank: machine-wide brute-force sort. 8 blocks/task; thread = one element ----
__global__ __launch_bounds__(256) void rank_k(const float* __restrict__ s2_all, int heads,
                                              float* __restrict__ g_sval, int* __restrict__ g_sidx) {
    __shared__ unsigned long long pk[NSEG];
    const int tid = threadIdx.x;
    const int t = blockIdx.y, g = t / heads, h = t % heads;
    const float* s2p = s2_all + (size_t)h * NTOT + (size_t)g * NSEG;
    for (int i = tid; i < NSEG; i += 256) pk[i] = pack_key(s2p[i], i);
    __syncthreads();
    const int e = blockIdx.x * 256 + tid;
    const unsigned long long my = pk[e];
    int cnt = 0;
#pragma unroll 8
    for (int j = 0; j < NSEG; ++j) cnt += (pk[j] < my) ? 1 : 0;
    g_sval[(size_t)t * NSEG + cnt] = unpack_key(my);
    g_sidx[(size_t)t * NSEG + cnt] = e;
}

// ---- chunkv: wave per chunk; gather V -> Vst, raw weighted chunk sums ----
__global__ __launch_bounds__(256) void chunkv_k(const float* __restrict__ V,
                                                int heads, int vstride,
                                                const float* __restrict__ g_sval,
                                                const int* __restrict__ g_sidx,
                                                float* __restrict__ g_chA, float* __restrict__ g_chS,
                                                float* __restrict__ g_Vs) {
    const int t = blockIdx.y, g = t / heads, h = t % heads;
    const int wv = threadIdx.x >> 6, lane = threadIdx.x & 63;
    const int c = blockIdx.x * 4 + wv, base = c * 16;
    const float* Vp = V + (size_t)g * NSEG * vstride + h * 64;
    float* Vst = g_Vs + (size_t)t * NSEG * 64;
    const float M2 = g_sval[(size_t)t * NSEG + NSEG - 1];
    float sv_l = 0.f; int si_l = 0;
    if (lane < 16) {
        sv_l = g_sval[(size_t)t * NSEG + base + lane];
        si_l = g_sidx[(size_t)t * NSEG + base + lane];
    }
    float sa = 0.f, swa = 0.f, ss = 0.f, sws = 0.f;
#pragma unroll
    for (int j = 0; j < 16; ++j) {
        float sv = __shfl(sv_l, j, 64);
        int row = __shfl(si_l, j, 64);
        float wn = __expf(0.2f * (sv - M2));
        float w2 = wn * wn, wp = w2 * w2 * wn;
        float v = Vp[(size_t)row * vstride + lane];
        Vst[(size_t)(base + j) * 64 + lane] = v;
        sa += wn * v; swa += wn;
        ss += wp * v; sws += wp;
    }
    size_t oo = (size_t)t * CROWS + (size_t)c * 65;
    g_chA[oo + lane] = sa;
    g_chS[oo + lane] = ss;
    if (lane == 0) { g_chA[oo + 64] = swa; g_chS[oo + 64] = sws; }
}

// ---- scan: per-task 3-phase scans of the 128 chunk rows (verified R8 phase C) ----
__global__ __launch_bounds__(1024) void scan_k(float* __restrict__ g_chA, float* __restrict__ g_chS) {
    __shared__ float chA[8320];
    __shared__ float chS[8320];
    __shared__ float btA[4][65];
    __shared__ float btS[4][65];
    const int t = blockIdx.x, tid = threadIdx.x;
    for (int i = tid; i < 8320; i += 1024) {
        chA[i] = g_chA[(size_t)t * CROWS + i];
        chS[i] = g_chS[(size_t)t * CROWS + i];
    }
    __syncthreads();
    if (tid < 260) {
        int b = tid / 65, d = tid % 65;
        float run = 0.f;
        for (int c = b * 32; c < b * 32 + 32; ++c) { float v = chA[c * 65 + d]; chA[c * 65 + d] = run; run += v; }
        btA[b][d] = run;
    } else if (tid >= 512 && tid < 772) {
        int u = tid - 512;
        int b = u / 65, d = u % 65;
        float run = 0.f;
        for (int c = b * 32 + 31; c >= b * 32; --c) { run += chS[c * 65 + d]; chS[c * 65 + d] = run; }
        btS[b][d] = run;
    }
    __syncthreads();
    if (tid < 65) {
        float run = 0.f;
        for (int b = 0; b < 4; ++b) { float v = btA[b][tid]; btA[b][tid] = run; run += v; }
        g_chA[(size_t)t * CROWS + 8320 + tid] = run;   // row 128: total
    } else if (tid >= 512 && tid < 577) {
        int d = tid - 512;
        float run = 0.f;
        for (int b = 3; b >= 0; --b) { float v = btS[b][d]; btS[b][d] = run; run += v; }
        g_chS[(size_t)t * CROWS + 8320 + d] = 0.f;     // row 128: empty suffix
    }
    __syncthreads();
    if (tid < 512) {
        for (int i = tid; i < 8320; i += 512) chA[i] += btA[(i / 65) >> 5][i % 65];
    } else {
        for (int i = tid - 512; i < 8320; i += 512) chS[i] += btS[(i / 65) >> 5][i % 65];
    }
    __syncthreads();
    for (int i = tid; i < 8320; i += 1024) {
        g_chA[(size_t)t * CROWS + i] = chA[i];
        g_chS[(size_t)t * CROWS + i] = chS[i];
    }
}

// ---- serve: one query per wave, natural order; LDS-staged sval binary search ----
template <int MODE>  // 0: ELU -> xc ; 1: ELU + log_softmax -> out
__global__ __launch_bounds__(256) void tabquery_k(const float* __restrict__ s1_all,
                                                  int heads, int ostride,
                                                  const float* __restrict__ g_sval,
                                                  const float* __restrict__ g_chA,
                                                  const float* __restrict__ g_chS,
                                                  const float* __restrict__ g_Vs,
                                                  float* __restrict__ out) {
    __shared__ float ssv[NSEG];
    const int tid = threadIdx.x;
    const int t = blockIdx.y, g = t / heads, h = t % heads;
    const int wv = tid >> 6, lane = tid & 63;
    const float4* sv4 = (const float4*)(g_sval + (size_t)t * NSEG);
    for (int i = tid; i < NSEG / 4; i += 256) ((float4*)ssv)[i] = sv4[i];
    __syncthreads();
    const float M2 = ssv[NSEG - 1];
    const int q = blockIdx.x * 4 + wv;  // natural-order query row
    const float s1q = s1_all[(size_t)h * NTOT + (size_t)g * NSEG + q];
    const float th = -s1q;
    int lo = 0, hi = NSEG;
    while (lo < hi) { int mid = (lo + hi) >> 1; if (ssv[mid] <= th) lo = mid + 1; else hi = mid; }
    const int k = lo;
    int ck = k >> 4; if (ck > 127) ck = 127;
    const int base = ck * 16;
    const float* rA = g_chA + (size_t)t * CROWS + ck * 65;
    const float* rS = g_chS + (size_t)t * CROWS + (ck + 1) * 65;
    const float* Vst = g_Vs + (size_t)t * NSEG * 64 + (size_t)base * 64;
    float accA = rA[lane], scaA = rA[64];
    float accS = rS[lane], scaS = rS[64];
    float vv[16];
#pragma unroll
    for (int j = 0; j < 16; ++j) vv[j] = Vst[(size_t)j * 64 + lane];
#pragma unroll
    for (int j = 0; j < 16; ++j) {
        float wn = __expf(0.2f * (ssv[base + j] - M2));
        float w2 = wn * wn, wp = w2 * w2 * wn;
        bool isA = (base + j) < k;
        accA += isA ? wn * vv[j] : 0.f; scaA += isA ? wn : 0.f;
        accS += isA ? 0.f : wp * vv[j]; scaS += isA ? 0.f : wp;
    }
    float cc = __expf(-0.8f * fmaxf(s1q + M2, 0.f));
    float o = (accS + cc * accA) / (scaS + cc * scaA);
    o = o > 0.f ? o : expm1f(o);  // ELU
    float* outp = out + (size_t)g * NSEG * ostride + h * 64;
    if (MODE == 0) {
        outp[(size_t)q * ostride + lane] = o;
    } else {
        float m = o;
#pragma unroll
        for (int off = 32; off; off >>= 1) m = fmaxf(m, __shfl_xor(m, off, 64));
        float e = __expf(o - m);
#pragma unroll
        for (int off = 32; off; off >>= 1) e += __shfl_xor(e, off, 64);
        outp[(size_t)q * ostride + lane] = o - m - __logf(e);
    }
}

extern "C" void kernel_launch(void* const* d_in, const int* in_sizes, int n_in,
                              void* d_out, int out_size, void* d_ws, size_t ws_size,
                              hipStream_t stream) {
    const float* h_states = (const float*)d_in[0];
    const float* W_heads = (const float*)d_in[1];
    const float* a_heads = (const float*)d_in[2];
    const float* W_out = (const float*)d_in[3];
    const float* a_out = (const float*)d_in[4];
    float* w = (float*)d_ws;
    float* hh = w + OFF_HH;
    float* xc = w + OFF_XC;
    float* hc = w + OFF_HH;  // reuse: hh dead after layer-1 chunkv (V copied to Vs)
    float* s1h = w + OFF_S1H;
    float* s2h = w + OFF_S2H;
    float* s1o = w + OFF_S1O;
    float* s2o = w + OFF_S2O;
    float* g_sval = w + OFF_SVAL;
    int* g_sidx = (int*)(w + OFF_SIDX);
    float* g_chA = w + OFF_CHA;
    float* g_chS = w + OFF_CHS;
    float* g_Vs = w + OFF_VS;
    float* outp = (float*)d_out;

    gemm1_k<<<dim3(256, 4), 256, 0, stream>>>(h_states, W_heads, a_heads, hh, s1h, s2h);
    rank_k<<<dim3(8, 32), 256, 0, stream>>>(s2h, 4, g_sval, g_sidx);
    chunkv_k<<<dim3(32, 32), 256, 0, stream>>>(hh, 4, 256, g_sval, g_sidx, g_chA, g_chS, g_Vs);
    scan_k<<<32, 1024, 0, stream>>>(g_chA, g_chS);
    tabquery_k<0><<<dim3(512, 32), 256, 0, stream>>>(s1h, 4, 256, g_sval, g_chA, g_chS, g_Vs, xc);
    gemm2_k<<<256, 256, 0, stream>>>(xc, W_out, a_out, hc, s1o, s2o);
    rank_k<<<dim3(8, 8), 256, 0, stream>>>(s2o, 1, g_sval, g_sidx);
    chunkv_k<<<dim3(32, 8), 256, 0, stream>>>(hc, 1, 64, g_sval, g_sidx, g_chA, g_chS, g_Vs);
    scan_k<<<8, 1024, 0, stream>>>(g_chA, g_chS);
    tabquery_k<1><<<dim3(512, 8), 256, 0, stream>>>(s1o, 1, 64, g_sval, g_chA, g_chS, g_Vs, outp);
}